// Round 3
// baseline (368.885 us; speedup 1.0000x reference)
//
#include <hip/hip_runtime.h>
#include <hip/hip_bf16.h>

typedef __attribute__((ext_vector_type(8))) short bf16x8;
typedef __attribute__((ext_vector_type(4))) float f32x4;

#define KDIM 512
#define NDIM 512
#define NKT 16 // K-tiles of 32

__device__ __forceinline__ unsigned int pack_bf16(float a, float b) {
  // exact small integers in f32 -> low 16 mantissa bits are zero, truncation exact
  return (__builtin_bit_cast(unsigned int, a) >> 16) |
         (__builtin_bit_cast(unsigned int, b) & 0xffff0000u);
}

// ---------------- weight quantization + fragment-reorder (512 rows, 1 wave each) ----
// Wq_arr layout: slot s = ((nc*16 + kt)*64 + lane), 8 bf16 per slot, where
// lane holds col = nc*16 + (lane&15), k = kt*32 + (lane>>4)*8 + e  (MFMA B-frag order)
__global__ __launch_bounds__(64)
void quant_w_kernel(const float* __restrict__ W, const float* __restrict__ bias,
                    const float* __restrict__ scale_x,
                    ushort* __restrict__ Wq_arr, float* __restrict__ bq,
                    float* __restrict__ so_out) {
  const int n = blockIdx.x; // output channel = GEMM col
  const int l = threadIdx.x;
  const float* row = W + (size_t)n * KDIM;
  float4 v0 = *(const float4*)(row + l * 8);
  float4 v1 = *(const float4*)(row + l * 8 + 4);
  float m = fmaxf(fmaxf(fmaxf(fabsf(v0.x), fabsf(v0.y)), fmaxf(fabsf(v0.z), fabsf(v0.w))),
                  fmaxf(fmaxf(fabsf(v1.x), fabsf(v1.y)), fmaxf(fabsf(v1.z), fabsf(v1.w))));
#pragma unroll
  for (int off = 32; off; off >>= 1) m = fmaxf(m, __shfl_xor(m, off, 64));
  const float scale = fmaxf(m, 1e-8f) / 127.0f; // IEEE f32 div, matches jnp
  float vals[8] = {v0.x, v0.y, v0.z, v0.w, v1.x, v1.y, v1.z, v1.w};
  unsigned int packed[4];
#pragma unroll
  for (int i = 0; i < 4; ++i) {
    float qa = fminf(fmaxf(rintf(vals[2 * i] / scale), -128.f), 127.f);
    float qb = fminf(fmaxf(rintf(vals[2 * i + 1] / scale), -128.f), 127.f);
    packed[i] = pack_bf16(qa, qb);
  }
  // this lane covers k = l*8 .. l*8+7  ->  kt = l>>2, frag-lane = (n&15) + (l&3)*16
  const size_t slot = ((size_t)(n >> 4) * 16 + (l >> 2)) * 64 + (n & 15) + (l & 3) * 16;
  *(uint4*)(Wq_arr + slot * 8) = make_uint4(packed[0], packed[1], packed[2], packed[3]);
  if (l == 0) {
    float so = scale * scale_x[0];
    so_out[n] = so;
    bq[n] = rintf(bias[n] / so); // |b_q| small, clip never active
  }
}

// ---------------- GEMM: no LDS, no barriers. A direct-fragment from global, ----------
// ---------------- B from frag-reordered Wq (L1/L2-hot), 2-deep reg dbuf.    ----------
__global__ __launch_bounds__(256, 4)
void gemm_kernel(const float* __restrict__ X, const ushort* __restrict__ Wqa,
                 const float* __restrict__ bq, float* __restrict__ Out) {
  const int nblk = gridDim.x;
  int swz = blockIdx.x;
  if ((nblk & 7) == 0) // XCD-chunked bijective swizzle (T1); nblk=4096 -> exact
    swz = (blockIdx.x & 7) * (nblk >> 3) + (blockIdx.x >> 3);
  const int bm = swz >> 3; // M/128 = 512 row-tiles
  const int bn = swz & 7;  // N/64  = 8  col-tiles (siblings adjacent -> same XCD L2)

  const int tid = threadIdx.x;
  const int l = tid & 63, w = tid >> 6;
  const int lr = l & 15, lk = l >> 4;

  const int wrow0 = bm * 128 + w * 32; // wave owns 32 rows x 64 cols
  const int nc0 = bn * 4;              // col/16 base

  // A fragment pointers: lane reads rows (wrow0 + mf*16 + lr), k = kt*32 + lk*8 .. +7
  // wave-level: 16 consecutive rows x full 128B k-chunks -> every line fully used
  const float* x0 = X + (size_t)(wrow0 + lr) * KDIM + lk * 8;
  const float* x1 = x0 + (size_t)16 * KDIM;
  // B fragment base: slot ((nc0+nf)*16 + kt)*64 + l, 16B/lane, 1KB/load, L2-hot
  const ushort* bbase = Wqa + ((size_t)nc0 * 16 * 64 + l) * 8;

  f32x4 acc[2][4]; // [mf][nf] -> 32 regs (AGPR)
#pragma unroll
  for (int i = 0; i < 2; ++i)
#pragma unroll
    for (int j = 0; j < 4; ++j) acc[i][j] = (f32x4){0.f, 0.f, 0.f, 0.f};

  float4 Ab[2][4]; // [buf][mf*2+half] -- statically indexed under full unroll
  bf16x8 Bb[2][4]; // [buf][nf]

  auto loadA = [&](int kt, int buf) {
    Ab[buf][0] = *(const float4*)(x0 + kt * 32);
    Ab[buf][1] = *(const float4*)(x0 + kt * 32 + 4);
    Ab[buf][2] = *(const float4*)(x1 + kt * 32);
    Ab[buf][3] = *(const float4*)(x1 + kt * 32 + 4);
  };
  auto loadB = [&](int kt, int buf) {
#pragma unroll
    for (int nf = 0; nf < 4; ++nf)
      Bb[buf][nf] = *(const bf16x8*)(bbase + ((size_t)nf * 16 + kt) * 512);
  };

  loadA(0, 0); loadB(0, 0); // prefetch depth 2
  loadA(1, 1); loadB(1, 1);

#pragma unroll
  for (int kt = 0; kt < NKT; ++kt) {
    const int cur = kt & 1;
    bf16x8 af[2];
#pragma unroll
    for (int mf = 0; mf < 2; ++mf) { // pack A(kt): waits only its own 4 loads
      float4 a0 = Ab[cur][mf * 2], a1 = Ab[cur][mf * 2 + 1];
      union { unsigned int u[4]; bf16x8 v; } r;
      r.u[0] = pack_bf16(a0.x, a0.y);
      r.u[1] = pack_bf16(a0.z, a0.w);
      r.u[2] = pack_bf16(a1.x, a1.y);
      r.u[3] = pack_bf16(a1.z, a1.w);
      af[mf] = r.v;
    }
    if (kt + 2 < NKT) loadA(kt + 2, cur); // buffer freed by pack; ~2-iter distance
#pragma unroll
    for (int nf = 0; nf < 4; ++nf) { // waits B(kt), issued ~2 iters ago
      acc[0][nf] = __builtin_amdgcn_mfma_f32_16x16x32_bf16(af[0], Bb[cur][nf], acc[0][nf], 0, 0, 0);
      acc[1][nf] = __builtin_amdgcn_mfma_f32_16x16x32_bf16(af[1], Bb[cur][nf], acc[1][nf], 0, 0, 0);
    }
    if (kt + 2 < NKT) loadB(kt + 2, cur); // buffer freed by MFMAs above
  }

  // ---- epilogue: scalar stores (R1-proven exact WRITE_SIZE), bias in f32 exact ----
  const int colb = bn * 64;
  float bqv[4];
#pragma unroll
  for (int nf = 0; nf < 4; ++nf) bqv[nf] = bq[colb + nf * 16 + lr];
  // C/D layout (m89): row = lk*4 + e (+ mf*16), col = lr (+ nf*16)
  float* outp = Out + (size_t)(wrow0 + lk * 4) * NDIM + colb + lr;
#pragma unroll
  for (int mf = 0; mf < 2; ++mf)
#pragma unroll
    for (int nf = 0; nf < 4; ++nf)
#pragma unroll
      for (int e = 0; e < 4; ++e)
        outp[(size_t)(mf * 16 + e) * NDIM + nf * 16] = acc[mf][nf][e] + bqv[nf];
}

extern "C" void kernel_launch(void* const* d_in, const int* in_sizes, int n_in,
                              void* d_out, int out_size, void* d_ws, size_t ws_size,
                              hipStream_t stream) {
  const float* x = (const float*)d_in[0];
  const float* weight = (const float*)d_in[1];
  const float* bias = (const float*)d_in[2];
  const float* scale_x = (const float*)d_in[3];
  const int M = in_sizes[0] / KDIM; // 65536

  float* out = (float*)d_out;
  float* so_out = out + (size_t)M * NDIM;
  ushort* Wq_arr = (ushort*)d_ws;
  float* bq = (float*)((char*)d_ws + (size_t)NDIM * KDIM * sizeof(ushort));

  quant_w_kernel<<<NDIM, 64, 0, stream>>>(weight, bias, scale_x, Wq_arr, bq, so_out);

  const int blocks = (M / 128) * (NDIM / 64); // 4096
  gemm_kernel<<<blocks, 256, 0, stream>>>(x, Wq_arr, bq, out);
}

// Round 4
// 327.866 us; speedup vs baseline: 1.1251x; 1.1251x over previous
//
#include <hip/hip_runtime.h>
#include <hip/hip_bf16.h>

typedef __attribute__((ext_vector_type(8))) short bf16x8;
typedef __attribute__((ext_vector_type(4))) float f32x4;

#define KDIM 512
#define NDIM 512
#define BM 128
#define BN 64
#define BK 32
#define NT (KDIM / BK) // 16

__device__ __forceinline__ unsigned int pack_bf16(float a, float b) {
  // exact small integers in f32 -> low 16 mantissa bits are zero, truncation exact
  return (__builtin_bit_cast(unsigned int, a) >> 16) |
         (__builtin_bit_cast(unsigned int, b) & 0xffff0000u);
}

// ---------------- weight quantization + fragment-reorder (512 rows, 1 wave each) ----
// Wq_arr layout: slot s = ((nc*16 + kt)*64 + lane), 8 bf16 per slot, where
// lane holds col = nc*16 + (lane&15), k = kt*32 + (lane>>4)*8 + e  (MFMA B-frag order)
__global__ __launch_bounds__(64)
void quant_w_kernel(const float* __restrict__ W, const float* __restrict__ bias,
                    const float* __restrict__ scale_x,
                    ushort* __restrict__ Wq_arr, float* __restrict__ bq,
                    float* __restrict__ so_out) {
  const int n = blockIdx.x; // output channel = GEMM col
  const int l = threadIdx.x;
  const float* row = W + (size_t)n * KDIM;
  float4 v0 = *(const float4*)(row + l * 8);
  float4 v1 = *(const float4*)(row + l * 8 + 4);
  float m = fmaxf(fmaxf(fmaxf(fabsf(v0.x), fabsf(v0.y)), fmaxf(fabsf(v0.z), fabsf(v0.w))),
                  fmaxf(fmaxf(fabsf(v1.x), fabsf(v1.y)), fmaxf(fabsf(v1.z), fabsf(v1.w))));
#pragma unroll
  for (int off = 32; off; off >>= 1) m = fmaxf(m, __shfl_xor(m, off, 64));
  const float scale = fmaxf(m, 1e-8f) / 127.0f; // IEEE f32 div, matches jnp
  float vals[8] = {v0.x, v0.y, v0.z, v0.w, v1.x, v1.y, v1.z, v1.w};
  unsigned int packed[4];
#pragma unroll
  for (int i = 0; i < 4; ++i) {
    float qa = fminf(fmaxf(rintf(vals[2 * i] / scale), -128.f), 127.f);
    float qb = fminf(fmaxf(rintf(vals[2 * i + 1] / scale), -128.f), 127.f);
    packed[i] = pack_bf16(qa, qb);
  }
  // this lane covers k = l*8 .. l*8+7  ->  kt = l>>2, frag-lane = (n&15) + (l&3)*16
  const size_t slot = ((size_t)(n >> 4) * 16 + (l >> 2)) * 64 + (n & 15) + (l & 3) * 16;
  *(uint4*)(Wq_arr + slot * 8) = make_uint4(packed[0], packed[1], packed[2], packed[3]);
  if (l == 0) {
    float so = scale * scale_x[0];
    so_out[n] = so;
    bq[n] = rintf(bias[n] / so); // |b_q| small, clip never active
  }
}

// ---------------- GEMM ----------------------------------------------------------------
// A: f32 staged via global_load_lds (fire-and-forget), pre-swizzled source (m173/rule21),
//    f32->bf16 pack on LDS-read side (overlaps MFMA).
// B: direct from frag-reordered Wq_arr (512KB, L1/L2-hot).
// 32KB LDS/block -> 5 blocks/CU: cross-block TLP covers the per-step barrier drain.
__global__ __launch_bounds__(256, 5)
void gemm_kernel(const float* __restrict__ X, const ushort* __restrict__ Wqa,
                 const float* __restrict__ bq, float* __restrict__ Out) {
  __shared__ __align__(16) float As[2][BM * BK]; // 2 x 16KB, [row][k] f32, src-swizzled

  const int nblk = gridDim.x;
  int swz = blockIdx.x;
  if ((nblk & 7) == 0) // XCD-chunked bijective swizzle (T1); nblk=4096 exact
    swz = (blockIdx.x & 7) * (nblk >> 3) + (blockIdx.x >> 3);
  const int bm = swz >> 3; // 512 row-tiles
  const int bn = swz & 7;  // 8 col-tiles; siblings adjacent -> same XCD -> A reuse in L2

  const int tid = threadIdx.x;
  const int l = tid & 63, w = tid >> 6;
  const int lr = l & 15, lk = l >> 4;

  const float* xbase = X + (size_t)bm * BM * KDIM;
  // B frag base: slot ((nc*16 + t)*64 + l), nc = bn*4 + nf
  const ushort* bbase = Wqa + (((size_t)bn * 4 * 16) * 64 + l) * 8;

  f32x4 acc[2][4]; // wave tile 32 rows x 64 cols
#pragma unroll
  for (int i = 0; i < 2; ++i)
#pragma unroll
    for (int j = 0; j < 4; ++j) acc[i][j] = (f32x4){0.f, 0.f, 0.f, 0.f};

  // stage K-step t into buf: 128 rows x 32 f32 = 16KB = 1024 16B-slots, 4 per thread.
  // LDS dest linear in lane order (m104); SOURCE chunk is XOR-swizzled so that the
  // read side gets conflict-free ds_read_b128 (both-sides-or-neither, rule #21).
  auto stage = [&](int t, int buf) {
#pragma unroll
    for (int i = 0; i < 4; ++i) {
      int s = i * 256 + tid;     // 16B slot
      int row = s >> 3;          // 8 slots per 128B row
      int c = s & 7;
      int sc = c ^ (row & 7);    // inverse-swizzled source chunk
      const float* g = xbase + (size_t)row * KDIM + t * BK + sc * 4;
      float* lp = &As[buf][0] + (size_t)s * 4;
      __builtin_amdgcn_global_load_lds(
          (const __attribute__((address_space(1))) unsigned int*)g,
          (__attribute__((address_space(3))) unsigned int*)lp, 16, 0, 0);
    }
  };

  auto compute = [&](int t, int buf) {
    const char* pA = (const char*)&As[buf][0];
    bf16x8 bf[4];
#pragma unroll
    for (int nf = 0; nf < 4; ++nf) // 1KB lane-linear, L1-hot (all 4 waves same lines)
      bf[nf] = *(const bf16x8*)(bbase + ((size_t)nf * 16 + t) * 512);
    bf16x8 af[2];
#pragma unroll
    for (int mf = 0; mf < 2; ++mf) { // rows w*32 + mf*16 + lr, k = lk*8..lk*8+7
      int r = w * 32 + mf * 16 + lr;
      int swzr = (r & 7) << 4;
      float4 lo = *(const float4*)(pA + (r * 128 + (((lk * 2) << 4) ^ swzr)));
      float4 hi = *(const float4*)(pA + (r * 128 + (((lk * 2 + 1) << 4) ^ swzr)));
      union { unsigned int u[4]; bf16x8 v; } rr;
      rr.u[0] = pack_bf16(lo.x, lo.y);
      rr.u[1] = pack_bf16(lo.z, lo.w);
      rr.u[2] = pack_bf16(hi.x, hi.y);
      rr.u[3] = pack_bf16(hi.z, hi.w);
      af[mf] = rr.v;
    }
#pragma unroll
    for (int mf = 0; mf < 2; ++mf)
#pragma unroll
      for (int nf = 0; nf < 4; ++nf)
        acc[mf][nf] = __builtin_amdgcn_mfma_f32_16x16x32_bf16(af[mf], bf[nf],
                                                              acc[mf][nf], 0, 0, 0);
  };

  // T3-minimal: issue STAGE(next) before compute; one barrier per K-step drains it.
  stage(0, 0);
  __syncthreads();
  for (int t = 0; t < NT; ++t) {
    if (t < NT - 1) stage(t + 1, (t + 1) & 1);
    compute(t, t & 1);
    __syncthreads(); // drains vmcnt (stage t+1 landed) + guards buf reuse
  }

  // ---- epilogue: scalar stores (R3-proven exact WRITE_SIZE), bias add exact in f32 ----
  const int colb = bn * BN;
  float bqv[4];
#pragma unroll
  for (int nf = 0; nf < 4; ++nf) bqv[nf] = bq[colb + nf * 16 + lr];
  const int wrow0 = bm * BM + w * 32;
  // C/D layout (m89): row = lk*4 + e (+ mf*16), col = lr (+ nf*16)
  float* outp = Out + (size_t)(wrow0 + lk * 4) * NDIM + colb + lr;
#pragma unroll
  for (int mf = 0; mf < 2; ++mf)
#pragma unroll
    for (int nf = 0; nf < 4; ++nf)
#pragma unroll
      for (int e = 0; e < 4; ++e)
        outp[(size_t)(mf * 16 + e) * NDIM + nf * 16] = acc[mf][nf][e] + bqv[nf];
}

extern "C" void kernel_launch(void* const* d_in, const int* in_sizes, int n_in,
                              void* d_out, int out_size, void* d_ws, size_t ws_size,
                              hipStream_t stream) {
  const float* x = (const float*)d_in[0];
  const float* weight = (const float*)d_in[1];
  const float* bias = (const float*)d_in[2];
  const float* scale_x = (const float*)d_in[3];
  const int M = in_sizes[0] / KDIM; // 65536

  float* out = (float*)d_out;
  float* so_out = out + (size_t)M * NDIM;
  ushort* Wq_arr = (ushort*)d_ws;
  float* bq = (float*)((char*)d_ws + (size_t)NDIM * KDIM * sizeof(ushort));

  quant_w_kernel<<<NDIM, 64, 0, stream>>>(weight, bias, scale_x, Wq_arr, bq, so_out);

  const int blocks = (M / BM) * (NDIM / BN); // 4096
  gemm_kernel<<<blocks, 256, 0, stream>>>(x, Wq_arr, bq, out);
}

// Round 6
// 323.611 us; speedup vs baseline: 1.1399x; 1.0131x over previous
//
#include <hip/hip_runtime.h>
#include <hip/hip_bf16.h>

typedef __attribute__((ext_vector_type(8))) short bf16x8;
typedef __attribute__((ext_vector_type(4))) float f32x4;

#define KDIM 512
#define NDIM 512
#define BM 128
#define BN 64
#define BK 32
#define NT (KDIM / BK) // 16
#define NBUF 4

__device__ __forceinline__ unsigned int pack_bf16(float a, float b) {
  // exact small integers in f32 -> low 16 mantissa bits are zero, truncation exact
  return (__builtin_bit_cast(unsigned int, a) >> 16) |
         (__builtin_bit_cast(unsigned int, b) & 0xffff0000u);
}

// ---------------- weight quantization + fragment-reorder (512 rows, 1 wave each) ----
// Wq_arr layout: slot s = ((nc*16 + kt)*64 + lane), 8 bf16 per slot, where
// lane holds col = nc*16 + (lane&15), k = kt*32 + (lane>>4)*8 + e  (MFMA B-frag order)
__global__ __launch_bounds__(64)
void quant_w_kernel(const float* __restrict__ W, const float* __restrict__ bias,
                    const float* __restrict__ scale_x,
                    ushort* __restrict__ Wq_arr, float* __restrict__ bq,
                    float* __restrict__ so_out) {
  const int n = blockIdx.x; // output channel = GEMM col
  const int l = threadIdx.x;
  const float* row = W + (size_t)n * KDIM;
  float4 v0 = *(const float4*)(row + l * 8);
  float4 v1 = *(const float4*)(row + l * 8 + 4);
  float m = fmaxf(fmaxf(fmaxf(fabsf(v0.x), fabsf(v0.y)), fmaxf(fabsf(v0.z), fabsf(v0.w))),
                  fmaxf(fmaxf(fabsf(v1.x), fabsf(v1.y)), fmaxf(fabsf(v1.z), fabsf(v1.w))));
#pragma unroll
  for (int off = 32; off; off >>= 1) m = fmaxf(m, __shfl_xor(m, off, 64));
  const float scale = fmaxf(m, 1e-8f) / 127.0f; // IEEE f32 div, matches jnp
  float vals[8] = {v0.x, v0.y, v0.z, v0.w, v1.x, v1.y, v1.z, v1.w};
  unsigned int packed[4];
#pragma unroll
  for (int i = 0; i < 4; ++i) {
    float qa = fminf(fmaxf(rintf(vals[2 * i] / scale), -128.f), 127.f);
    float qb = fminf(fmaxf(rintf(vals[2 * i + 1] / scale), -128.f), 127.f);
    packed[i] = pack_bf16(qa, qb);
  }
  // this lane covers k = l*8 .. l*8+7  ->  kt = l>>2, frag-lane = (n&15) + (l&3)*16
  const size_t slot = ((size_t)(n >> 4) * 16 + (l >> 2)) * 64 + (n & 15) + (l & 3) * 16;
  *(uint4*)(Wq_arr + slot * 8) = make_uint4(packed[0], packed[1], packed[2], packed[3]);
  if (l == 0) {
    float so = scale * scale_x[0];
    so_out[n] = so;
    bq[n] = rintf(bias[n] / so); // |b_q| small, clip never active
  }
}

// ---------------- GEMM ----------------------------------------------------------------
// T3+T4: 4-deep LDS multibuffer, ALL staging via fire-and-forget global_load_lds,
// counted s_waitcnt vmcnt(10) (never 0 in main loop) + raw s_barrier (no auto-drain).
// A staged f32 (pack->bf16 on read side), B staged from frag-ordered Wq_arr.
__global__ __launch_bounds__(256, 2)
void gemm_kernel(const float* __restrict__ X, const ushort* __restrict__ Wqa,
                 const float* __restrict__ bq, float* __restrict__ Out) {
  __shared__ __align__(16) float As[NBUF][BM * BK];    // 4 x 16KB
  __shared__ __align__(16) ushort Bsh[NBUF][BN * BK];  // 4 x 4KB   (80KB -> 2 blk/CU)

  const int nblk = gridDim.x;
  int swz = blockIdx.x;
  if ((nblk & 7) == 0) // XCD-chunked bijective swizzle (T1); nblk=4096 exact
    swz = (blockIdx.x & 7) * (nblk >> 3) + (blockIdx.x >> 3);
  const int bm = swz >> 3; // 512 row-tiles
  const int bn = swz & 7;  // 8 col-tiles; siblings adjacent -> same XCD L2 A-reuse

  const int tid = threadIdx.x;
  const int l = tid & 63, w = tid >> 6;
  const int lr = l & 15, lk = l >> 4;

  const float* xbase = X + (size_t)bm * BM * KDIM;
  const ushort* wqbase = Wqa + (((size_t)(bn * 4 + w) * 16) * 64 + l) * 8; // this wave's nf=w panel

  f32x4 acc[2][4]; // wave tile 32 rows x 64 cols
#pragma unroll
  for (int i = 0; i < 2; ++i)
#pragma unroll
    for (int j = 0; j < 4; ++j) acc[i][j] = (f32x4){0.f, 0.f, 0.f, 0.f};

  // stage K-step t: A = 128x32 f32 (1024 16B slots, 4/thread, src chunk XOR-swizzled
  // so read side is conflict-free, rule #21); B = 4KB frag-ordered (1 slot/thread).
  auto stage = [&](int t, int buf) {
#pragma unroll
    for (int i = 0; i < 4; ++i) {
      int s = i * 256 + tid;   // 16B slot
      int row = s >> 3;
      int c = s & 7;
      int sc = c ^ (row & 7);  // inverse-swizzle SOURCE, LDS dest linear (m104/m173)
      const float* g = xbase + (size_t)row * KDIM + t * BK + sc * 4;
      float* lp = &As[buf][0] + (size_t)s * 4;
      __builtin_amdgcn_global_load_lds(
          (const __attribute__((address_space(1))) unsigned int*)g,
          (__attribute__((address_space(3))) unsigned int*)lp, 16, 0, 0);
    }
    { // B: wave w stages its own nf=w 1KB panel; lane-linear both sides
      const ushort* g = wqbase + (size_t)t * 512; // slot stride 64*8 ushorts per kt
      ushort* lp = &Bsh[buf][0] + (size_t)tid * 8;
      __builtin_amdgcn_global_load_lds(
          (const __attribute__((address_space(1))) unsigned int*)g,
          (__attribute__((address_space(3))) unsigned int*)lp, 16, 0, 0);
    }
  };

  auto compute = [&](int buf) {
    const char* pA = (const char*)&As[buf][0];
    const ushort* pB = &Bsh[buf][0];
    bf16x8 bf[4];
#pragma unroll
    for (int nf = 0; nf < 4; ++nf) // lane-linear ds_read_b128, 2-way (free)
      bf[nf] = *(const bf16x8*)(pB + ((size_t)nf * 64 + l) * 8);
    bf16x8 af[2];
#pragma unroll
    for (int mf = 0; mf < 2; ++mf) { // rows w*32 + mf*16 + lr, k = lk*8..+7
      int r = w * 32 + mf * 16 + lr;
      int swzr = (r & 7) << 4;
      float4 lo = *(const float4*)(pA + (r * 128 + (((lk * 2) << 4) ^ swzr)));
      float4 hi = *(const float4*)(pA + (r * 128 + (((lk * 2 + 1) << 4) ^ swzr)));
      union { unsigned int u[4]; bf16x8 v; } rr;
      rr.u[0] = pack_bf16(lo.x, lo.y);
      rr.u[1] = pack_bf16(lo.z, lo.w);
      rr.u[2] = pack_bf16(hi.x, hi.y);
      rr.u[3] = pack_bf16(hi.z, hi.w);
      af[mf] = rr.v;
    }
#pragma unroll
    for (int mf = 0; mf < 2; ++mf)
#pragma unroll
      for (int nf = 0; nf < 4; ++nf)
        acc[mf][nf] = __builtin_amdgcn_mfma_f32_16x16x32_bf16(af[mf], bf[nf],
                                                              acc[mf][nf], 0, 0, 0);
  };

  // prologue: 2 steps in flight before first wait
  stage(0, 0);
  stage(1, 1);

  // steady state per step: [stage(t+2)] -> vmcnt(10) (keep t+1,t+2 = 2x5 ops in
  // flight; drains t) -> raw s_barrier (no auto vmcnt(0)!) -> compute(t) ->
  // sched_barrier(0) pins MFMA/ds_read before next barrier (rule #18 guard).
#define STEP(T)                                                                     \
  {                                                                                 \
    if ((T) + 2 < NT) stage((T) + 2, ((T) + 2) & 3);                                \
    asm volatile("s_waitcnt vmcnt(%0)" ::"n"(                                       \
        ((T) + 2 < NT) ? 10 : (((T) + 1 < NT) ? 5 : 0)) : "memory");                \
    __builtin_amdgcn_s_barrier();                                                   \
    compute((T) & 3);                                                               \
    __builtin_amdgcn_sched_barrier(0);                                              \
  }
  STEP(0) STEP(1) STEP(2) STEP(3) STEP(4) STEP(5) STEP(6) STEP(7)
  STEP(8) STEP(9) STEP(10) STEP(11) STEP(12) STEP(13) STEP(14) STEP(15)
#undef STEP

  // ---- epilogue: scalar stores (proven exact WRITE_SIZE in R3), bias exact in f32 ----
  const int colb = bn * BN;
  float bqv[4];
#pragma unroll
  for (int nf = 0; nf < 4; ++nf) bqv[nf] = bq[colb + nf * 16 + lr];
  const int wrow0 = bm * BM + w * 32;
  // C/D layout (m89): row = lk*4 + e (+ mf*16), col = lr (+ nf*16)
  float* outp = Out + (size_t)(wrow0 + lk * 4) * NDIM + colb + lr;
#pragma unroll
  for (int mf = 0; mf < 2; ++mf)
#pragma unroll
    for (int nf = 0; nf < 4; ++nf)
#pragma unroll
      for (int e = 0; e < 4; ++e)
        outp[(size_t)(mf * 16 + e) * NDIM + nf * 16] = acc[mf][nf][e] + bqv[nf];
}

extern "C" void kernel_launch(void* const* d_in, const int* in_sizes, int n_in,
                              void* d_out, int out_size, void* d_ws, size_t ws_size,
                              hipStream_t stream) {
  const float* x = (const float*)d_in[0];
  const float* weight = (const float*)d_in[1];
  const float* bias = (const float*)d_in[2];
  const float* scale_x = (const float*)d_in[3];
  const int M = in_sizes[0] / KDIM; // 65536

  float* out = (float*)d_out;
  float* so_out = out + (size_t)M * NDIM;
  ushort* Wq_arr = (ushort*)d_ws;
  float* bq = (float*)((char*)d_ws + (size_t)NDIM * KDIM * sizeof(ushort));

  quant_w_kernel<<<NDIM, 64, 0, stream>>>(weight, bias, scale_x, Wq_arr, bq, so_out);

  const int blocks = (M / BM) * (NDIM / BN); // 4096
  gemm_kernel<<<blocks, 256, 0, stream>>>(x, Wq_arr, bq, out);
}